// Round 1
// baseline (482.121 us; speedup 1.0000x reference)
//
#include <hip/hip_runtime.h>
#include <hip/hip_bf16.h>

typedef _Float16 half8 __attribute__((ext_vector_type(8)));
typedef float f32x4 __attribute__((ext_vector_type(4)));

#define N_DETS 8192

// ---- workspace layout (offsets in _Float16 units unless noted) ----
#define OFF_W0P   0          // 16x1x512
#define OFF_W1P   8192       // 16x8x512
#define OFF_W2P   73728      // 2x8x512
#define OFF_FC1P  81920      // 8 x 4096
#define OFF_PW1P  114688     // 8 x 6144
#define OFF_PW2P  163840     // 8 x 4096
#define OFF_POSTP 196608     // 8 x 2 x 4096
#define OFF_OUTP  262144     // 8 x 8192
#define OFF_F1    327680     // 8192x32 f16
#define OFF_POOL  589824     // 8192x64 f16
#define OFF_PFP   1114112    // 32768 groups x 512 (packed A-frags of pairFeatures)
#define OFF_FBUF_BYTES 35782656  // f32 [8192][128]

__device__ inline f32x4 mfma16(half8 a, half8 b, f32x4 c){
  return __builtin_amdgcn_mfma_f32_16x16x32_f16(a, b, c, 0, 0, 0);
}
__device__ inline half8 ldg8(const _Float16* p){ return *(const half8*)p; }

// swizzled LDS tile helpers; SB = row stride in BYTES. Element (row,k) at
// byte row*SB + ((k*2) ^ ((row&7)<<4))  -> breaks the 16-way ds_read conflict.
template<int SB>
__device__ inline void swzSt(_Float16* buf, int row, int k, float v){
  *(_Float16*)((char*)buf + row*SB + (((k << 1) ^ ((row & 7) << 4)))) = (_Float16)v;
}
template<int SB>
__device__ inline half8 swzLd(const _Float16* buf, int row, int k0){
  return *(const half8*)((const char*)buf + row*SB + (((k0 << 1) ^ ((row & 7) << 4))));
}

// ---- weight packing: B-frag layout, per (ntile,ktile) tile = 64 lanes x 8 halfs ----
__device__ inline void packB(const float* W, int Ksrc, int Nn, _Float16* dst, int sig){
  int ns = (Ksrc + 31) >> 5;
  int t = sig / (ns * 64);
  int rem = sig - t * ns * 64;
  int s = rem >> 6;
  int l = rem & 63;
  int col = t * 16 + (l & 15);
  int k0 = s * 32 + ((l >> 4) << 3);
  half8 v;
#pragma unroll
  for (int j = 0; j < 8; ++j){
    int k = k0 + j;
    v[j] = (_Float16)((k < Ksrc) ? W[k * Nn + col] : 0.f);
  }
  *(half8*)(dst + sig * 8) = v;
}

__global__ __launch_bounds__(256) void kPrep(const float* pwW0, const float* pwW1, const float* pwW2,
    const float* fc1W, const float* pw1W, const float* pw2W, const float* postW, const float* outW,
    _Float16* wsh){
  int sig = blockIdx.x * 256 + threadIdx.x;
  if (sig < 1024){ packB(pwW0, 9, 256, wsh + OFF_W0P, sig); return; }
  sig -= 1024;
  if (sig < 8192){ packB(pwW1, 256, 256, wsh + OFF_W1P, sig); return; }
  sig -= 8192;
  if (sig < 1024){ packB(pwW2, 256, 32, wsh + OFF_W2P, sig); return; }
  sig -= 1024;
  int i = sig / 3840;
  int q = sig - i * 3840;
  if (q < 512){ packB(fc1W + i*4096, 128, 32, wsh + OFF_FC1P + i*4096, q); return; }
  q -= 512;
  if (q < 768){ packB(pw1W + i*6144, 96, 64, wsh + OFF_PW1P + i*6144, q); return; }
  q -= 768;
  if (q < 512){ packB(pw2W + i*4096, 64, 64, wsh + OFF_PW2P + i*4096, q); return; }
  q -= 512;
  if (q < 512){ packB(postW + i*8192, 64, 64, wsh + OFF_POSTP + i*8192, q); return; }
  q -= 512;
  if (q < 512){ packB(postW + i*8192 + 4096, 64, 64, wsh + OFF_POSTP + i*8192 + 4096, q); return; }
  q -= 512;
  packB(outW + i*8192, 64, 128, wsh + OFF_OUTP + i*8192, q);
}

// ---- fused pairwise feature MLP: raw(9) -> 256 -> 256 -> 32, per-WG 64 edges ----
__global__ __launch_bounds__(256) void kP(const float* scores, const float* boxes,
    const int* cI, const int* nI, const float* b0, const float* b1, const float* b2,
    const _Float16* W0p, const _Float16* W1p, const _Float16* W2p, _Float16* pfp){
  __shared__ __align__(16) _Float16 hbuf[64 * 256];   // per-wave 16-row slab, swizzled, stride 512B
  __shared__ __align__(16) _Float16 rawp[256 * 8];    // packed A-frags (also reused as pf stage)
  int tid = threadIdx.x;
  int wgbase = blockIdx.x * 64;
  {
    half8 z = {0,0,0,0,0,0,0,0};
    *(half8*)(rawp + tid * 8) = z;
  }
  __syncthreads();
  if (tid < 64){
    int e = wgbase + tid;
    int c = cI[e], n = nI[e];
    float cx1 = boxes[c*4+0], cy1 = boxes[c*4+1], cx2 = boxes[c*4+2], cy2 = boxes[c*4+3];
    float nx1 = boxes[n*4+0], ny1 = boxes[n*4+1], nx2 = boxes[n*4+2], ny2 = boxes[n*4+3];
    float cw = cx2-cx1, ch = cy2-cy1, nw = nx2-nx1, nh = ny2-ny1;
    float ca = cw*ch, na = nw*nh;
    float ix = fmaxf(fminf(cx2,nx2) - fmaxf(cx1,nx1), 0.f);
    float iy = fmaxf(fminf(cy2,ny2) - fmaxf(cy1,ny1), 0.f);
    float inter = ix*iy;
    float iou = inter / (ca + na - inter);
    float cs = (cw + ch) * 0.5f;
    float ccx = cx1 + cw*0.5f, ccy = cy1 + ch*0.5f;
    float ncx = nx1 + nw*0.5f, ncy = ny1 + nh*0.5f;
    float xd = ncx - ccx, yd = ncy - ccy;
    float l2 = sqrtf(xd*xd + yd*yd) / cs;
    float wd = log2f(nw/cw), hd = log2f(nh/ch);
    float ad = log2f(nw/nh) - log2f(cw/ch);
    float rv[9] = {scores[c], scores[n], iou, xd/cs, yd/cs, l2, wd, hd, ad};
    int g = tid >> 4, l0 = tid & 15;
#pragma unroll
    for (int j = 0; j < 8; ++j) rawp[(g*64 + l0)*8 + j] = (_Float16)rv[j];
    rawp[(g*64 + 16 + l0)*8 + 0] = (_Float16)rv[8];
  }
  __syncthreads();
  int wave = tid >> 6, lane = tid & 63;
  int colb = lane & 15;
  int khalf = (lane >> 4) << 3;
  int rW = wave * 16 + colb;        // A-frag row owned by this lane
  int r16 = (lane >> 4) << 2;       // C-frag row base within wave tile
  const f32x4 fz = {0.f, 0.f, 0.f, 0.f};

  // L0: raw(32 padded) -> 256
  f32x4 acc[16];
#pragma unroll
  for (int t = 0; t < 16; ++t) acc[t] = fz;
  {
    half8 a0 = *(const half8*)(rawp + (wave*64 + lane)*8);
#pragma unroll
    for (int t = 0; t < 16; ++t)
      acc[t] = mfma16(a0, ldg8(W0p + t*512 + lane*8), acc[t]);
  }
#pragma unroll
  for (int t = 0; t < 16; ++t){
    float bb = b0[t*16 + colb];
#pragma unroll
    for (int r = 0; r < 4; ++r)
      swzSt<512>(hbuf, wave*16 + r16 + r, t*16 + colb, fmaxf(acc[t][r] + bb, 0.f));
  }
  // L1: 256 -> 256 (B-frags streamed from global/L2)
#pragma unroll
  for (int t = 0; t < 16; ++t) acc[t] = fz;
#pragma unroll
  for (int s = 0; s < 8; ++s){
    half8 a = swzLd<512>(hbuf, rW, s*32 + khalf);
#pragma unroll
    for (int t = 0; t < 16; ++t)
      acc[t] = mfma16(a, ldg8(W1p + (t*8 + s)*512 + lane*8), acc[t]);
  }
#pragma unroll
  for (int t = 0; t < 16; ++t){
    float bb = b1[t*16 + colb];
#pragma unroll
    for (int r = 0; r < 4; ++r)
      swzSt<512>(hbuf, wave*16 + r16 + r, t*16 + colb, fmaxf(acc[t][r] + bb, 0.f));
  }
  // L2: 256 -> 32, emit packed-A pf
  f32x4 a2[2];
  a2[0] = fz; a2[1] = fz;
#pragma unroll
  for (int s = 0; s < 8; ++s){
    half8 a = swzLd<512>(hbuf, rW, s*32 + khalf);
#pragma unroll
    for (int t = 0; t < 2; ++t)
      a2[t] = mfma16(a, ldg8(W2p + (t*8 + s)*512 + lane*8), a2[t]);
  }
#pragma unroll
  for (int t = 0; t < 2; ++t){
    float bb = b2[t*16 + colb];
#pragma unroll
    for (int r = 0; r < 4; ++r){
      float v = fmaxf(a2[t][r] + bb, 0.f);
      int n = t*16 + colb;
      rawp[(wave*64 + (r16 + r) + ((n >> 3) << 4))*8 + (n & 7)] = (_Float16)v;
    }
  }
  // per-wave region: in-order LDS within wave makes this safe without a barrier
  *(half8*)(pfp + (blockIdx.x*4 + wave)*512 + lane*8) = *(const half8*)(rawp + (wave*64 + lane)*8);
}

// ---- initial f1 = relu(detFeatures @ fc1_W[0] + b) ----
__global__ __launch_bounds__(256) void kB1(const float* detF, const float* fc1W, const float* fc1b,
    _Float16* f1G){
  int idx = blockIdx.x * 256 + threadIdx.x;
  int nrow = idx >> 5, col = idx & 31;
  float s = fc1b[col];
  for (int k = 0; k < 128; ++k) s += detF[nrow*128 + k] * fc1W[k*32 + col];
  f1G[idx] = (_Float16)fmaxf(s, 0.f);
}

__global__ __launch_bounds__(256) void kCopy(const float* src, float* dst){
  int i = blockIdx.x * 256 + threadIdx.x;
  dst[i] = src[i];
}

// ---- per-block edge MLP + segment max: one wave per detection (64 edges) ----
__global__ __launch_bounds__(256) void kB2(const _Float16* pfp, const _Float16* f1G, _Float16* poolG,
    const int* cI, const int* nI, const _Float16* pw1p, const _Float16* pw2p,
    const float* bb1, const float* bb2){
  __shared__ __align__(16) _Float16 sW1[6144];
  __shared__ __align__(16) _Float16 sW2[4096];
  __shared__ __align__(16) _Float16 wbuf[4][16 * 64];
  int tid = threadIdx.x;
  for (int u = tid; u < 1280; u += 256){
    if (u < 768) *(half8*)(sW1 + u*8) = ldg8(pw1p + u*8);
    else         *(half8*)(sW2 + (u-768)*8) = ldg8(pw2p + (u-768)*8);
  }
  __syncthreads();
  int wave = tid >> 6, lane = tid & 63;
  int det = blockIdx.x * 4 + wave;
  int colb = lane & 15;
  int khalf = (lane >> 4) << 3;
  int r16 = (lane >> 4) << 2;
  _Float16* wb = wbuf[wave];
  const f32x4 fz = {0.f, 0.f, 0.f, 0.f};
  f32x4 pmax[4];
#pragma unroll
  for (int t = 0; t < 4; ++t) pmax[t] = fz;

  for (int m = 0; m < 4; ++m){
    int ebase = det*64 + m*16;
    half8 aPF = ldg8(pfp + (det*4 + m)*512 + lane*8);
    int c = cI[ebase + colb];
    int n = nI[ebase + colb];
    half8 aC = ldg8(f1G + c*32 + khalf);
    half8 aN = ldg8(f1G + n*32 + khalf);
    f32x4 acc[4];
#pragma unroll
    for (int t = 0; t < 4; ++t) acc[t] = fz;
#pragma unroll
    for (int t = 0; t < 4; ++t){
      acc[t] = mfma16(aPF, *(const half8*)(sW1 + (t*3+0)*512 + lane*8), acc[t]);
      acc[t] = mfma16(aC,  *(const half8*)(sW1 + (t*3+1)*512 + lane*8), acc[t]);
      acc[t] = mfma16(aN,  *(const half8*)(sW1 + (t*3+2)*512 + lane*8), acc[t]);
    }
#pragma unroll
    for (int t = 0; t < 4; ++t){
      float bb = bb1[t*16 + colb];
#pragma unroll
      for (int r = 0; r < 4; ++r)
        swzSt<128>(wb, r16 + r, t*16 + colb, fmaxf(acc[t][r] + bb, 0.f));
    }
    f32x4 a2[4];
#pragma unroll
    for (int t = 0; t < 4; ++t) a2[t] = fz;
#pragma unroll
    for (int s = 0; s < 2; ++s){
      half8 a = swzLd<128>(wb, colb, s*32 + khalf);
#pragma unroll
      for (int t = 0; t < 4; ++t)
        a2[t] = mfma16(a, *(const half8*)(sW2 + (t*2+s)*512 + lane*8), a2[t]);
    }
#pragma unroll
    for (int t = 0; t < 4; ++t){
      float bb = bb2[t*16 + colb];
#pragma unroll
      for (int r = 0; r < 4; ++r)
        pmax[t][r] = fmaxf(pmax[t][r], fmaxf(a2[t][r] + bb, 0.f));
    }
  }
#pragma unroll
  for (int t = 0; t < 4; ++t){
    float v = fmaxf(fmaxf(pmax[t][0], pmax[t][1]), fmaxf(pmax[t][2], pmax[t][3]));
    v = fmaxf(v, __shfl_xor(v, 16));
    v = fmaxf(v, __shfl_xor(v, 32));
    if (lane < 16) poolG[det*64 + t*16 + lane] = (_Float16)v;
  }
}

// ---- per-block post MLPs + residual + next-block f1 (fused) ----
__global__ __launch_bounds__(256) void kB3(const _Float16* poolG, const float* fin, float* fout,
    _Float16* f1G, const _Float16* post0p, const _Float16* post1p, const _Float16* outp,
    const _Float16* fc1pn, const float* pb0, const float* pb1, const float* ob,
    const float* fbn, int doF1){
  __shared__ __align__(16) _Float16 wbuf[4][16 * 128];
  int tid = threadIdx.x;
  int wave = tid >> 6, lane = tid & 63;
  int rbase = blockIdx.x * 64 + wave * 16;
  int colb = lane & 15;
  int khalf = (lane >> 4) << 3;
  int r16 = (lane >> 4) << 2;
  _Float16* wb = wbuf[wave];
  const f32x4 fz = {0.f, 0.f, 0.f, 0.f};
  // p1 = relu(pool @ post0 + b)
  f32x4 acc[4];
#pragma unroll
  for (int t = 0; t < 4; ++t) acc[t] = fz;
#pragma unroll
  for (int s = 0; s < 2; ++s){
    half8 a = ldg8(poolG + (rbase + colb)*64 + s*32 + khalf);
#pragma unroll
    for (int t = 0; t < 4; ++t)
      acc[t] = mfma16(a, ldg8(post0p + (t*2+s)*512 + lane*8), acc[t]);
  }
#pragma unroll
  for (int t = 0; t < 4; ++t){
    float bb = pb0[t*16 + colb];
#pragma unroll
    for (int r = 0; r < 4; ++r)
      swzSt<256>(wb, r16 + r, t*16 + colb, fmaxf(acc[t][r] + bb, 0.f));
  }
  // p2 = relu(p1 @ post1 + b)
#pragma unroll
  for (int t = 0; t < 4; ++t) acc[t] = fz;
#pragma unroll
  for (int s = 0; s < 2; ++s){
    half8 a = swzLd<256>(wb, colb, s*32 + khalf);
#pragma unroll
    for (int t = 0; t < 4; ++t)
      acc[t] = mfma16(a, ldg8(post1p + (t*2+s)*512 + lane*8), acc[t]);
  }
#pragma unroll
  for (int t = 0; t < 4; ++t){
    float bb = pb1[t*16 + colb];
#pragma unroll
    for (int r = 0; r < 4; ++r)
      swzSt<256>(wb, r16 + r, t*16 + colb, fmaxf(acc[t][r] + bb, 0.f));
  }
  // fnew = relu(f + p2 @ outW + b)
  f32x4 a3[8];
#pragma unroll
  for (int t = 0; t < 8; ++t) a3[t] = fz;
#pragma unroll
  for (int s = 0; s < 2; ++s){
    half8 a = swzLd<256>(wb, colb, s*32 + khalf);
#pragma unroll
    for (int t = 0; t < 8; ++t)
      a3[t] = mfma16(a, ldg8(outp + (t*2+s)*512 + lane*8), a3[t]);
  }
#pragma unroll
  for (int t = 0; t < 8; ++t){
    float bb = ob[t*16 + colb];
#pragma unroll
    for (int r = 0; r < 4; ++r){
      int row = rbase + r16 + r;
      int col = t*16 + colb;
      float v = fmaxf(fin[row*128 + col] + a3[t][r] + bb, 0.f);
      fout[row*128 + col] = v;
      swzSt<256>(wb, r16 + r, col, v);
    }
  }
  if (doF1){
    f32x4 a4[2];
    a4[0] = fz; a4[1] = fz;
#pragma unroll
    for (int s = 0; s < 4; ++s){
      half8 a = swzLd<256>(wb, colb, s*32 + khalf);
#pragma unroll
      for (int t = 0; t < 2; ++t)
        a4[t] = mfma16(a, ldg8(fc1pn + (t*4+s)*512 + lane*8), a4[t]);
    }
#pragma unroll
    for (int t = 0; t < 2; ++t){
      float bb = fbn[t*16 + colb];
#pragma unroll
      for (int r = 0; r < 4; ++r)
        f1G[(rbase + r16 + r)*32 + t*16 + colb] = (_Float16)fmaxf(a4[t][r] + bb, 0.f);
    }
  }
}

extern "C" void kernel_launch(void* const* d_in, const int* in_sizes, int n_in,
                              void* d_out, int out_size, void* d_ws, size_t ws_size,
                              hipStream_t stream){
  const float* detScores   = (const float*)d_in[0];
  const float* dtBoxes     = (const float*)d_in[1];
  const float* detFeatures = (const float*)d_in[2];
  const int*   cI          = (const int*)d_in[3];
  const int*   nI          = (const int*)d_in[4];
  const float* pwW0 = (const float*)d_in[5];
  const float* pwb0 = (const float*)d_in[6];
  const float* pwW1 = (const float*)d_in[7];
  const float* pwb1 = (const float*)d_in[8];
  const float* pwW2 = (const float*)d_in[9];
  const float* pwb2 = (const float*)d_in[10];
  const float* fc1W = (const float*)d_in[11];
  const float* fc1b = (const float*)d_in[12];
  const float* pw1W = (const float*)d_in[13];
  const float* pw1b = (const float*)d_in[14];
  const float* pw2W = (const float*)d_in[15];
  const float* pw2b = (const float*)d_in[16];
  const float* postW = (const float*)d_in[17];
  const float* postb = (const float*)d_in[18];
  const float* outW  = (const float*)d_in[19];
  const float* outb  = (const float*)d_in[20];

  _Float16* wsh  = (_Float16*)d_ws;
  float*    fbuf = (float*)((char*)d_ws + OFF_FBUF_BYTES);
  _Float16* f1G   = wsh + OFF_F1;
  _Float16* poolG = wsh + OFF_POOL;
  _Float16* pfp   = wsh + OFF_PFP;

  kPrep<<<160, 256, 0, stream>>>(pwW0, pwW1, pwW2, fc1W, pw1W, pw2W, postW, outW, wsh);
  kCopy<<<4096, 256, 0, stream>>>(detFeatures, fbuf);
  kB1<<<1024, 256, 0, stream>>>(detFeatures, fc1W, fc1b, f1G);
  kP<<<8192, 256, 0, stream>>>(detScores, dtBoxes, cI, nI, pwb0, pwb1, pwb2,
      wsh + OFF_W0P, wsh + OFF_W1P, wsh + OFF_W2P, pfp);

  for (int i = 0; i < 8; ++i){
    kB2<<<2048, 256, 0, stream>>>(pfp, f1G, poolG, cI, nI,
        wsh + OFF_PW1P + i*6144, wsh + OFF_PW2P + i*4096, pw1b + i*64, pw2b + i*64);
    int last = (i == 7);
    kB3<<<128, 256, 0, stream>>>(poolG, fbuf, last ? (float*)d_out : fbuf, f1G,
        wsh + OFF_POSTP + i*8192, wsh + OFF_POSTP + i*8192 + 4096, wsh + OFF_OUTP + i*8192,
        wsh + OFF_FC1P + ((i+1) & 7)*4096,
        postb + i*128, postb + i*128 + 64, outb + i*128,
        fc1b + ((i+1) & 7)*32, last ? 0 : 1);
  }
}

// Round 2
// 365.291 us; speedup vs baseline: 1.3198x; 1.3198x over previous
//
#include <hip/hip_runtime.h>
#include <hip/hip_bf16.h>

typedef _Float16 half8 __attribute__((ext_vector_type(8)));
typedef float f32x4 __attribute__((ext_vector_type(4)));

#define N_DETS 8192

// ---- workspace layout (offsets in _Float16 units unless noted) ----
#define OFF_W0P   0          // 16 frags x 512 (k=9 row holds pw_b0)
#define OFF_W1P   8192       // 16x8x512
#define OFF_W2P   73728      // 2x8x512
#define OFF_FC1P  81920      // 8 x (2x4x512)
#define OFF_PW1P  114688     // 8 x (4x3x512)
#define OFF_PW2P  163840     // 8 x (4x2x512)
#define OFF_POSTP 196608     // 8 x 2 x (4x2x512)
#define OFF_OUTP  262144     // 8 x (8x2x512)
#define OFF_F1    327680     // 8192x32 f16 row-major
#define OFF_POOL  589824     // 8192x64 f16 row-major
#define OFF_PFP   1114112    // 32768 edge-tiles x 512 (frags: row/col=edge, k=neuron)
#define OFF_FBUF_BYTES 35782656  // f32 [8192][128]

__device__ inline f32x4 mfma16(half8 a, half8 b, f32x4 c){
  return __builtin_amdgcn_mfma_f32_16x16x32_f16(a, b, c, 0, 0, 0);
}
__device__ inline half8 ldg8(const _Float16* p){ return *(const half8*)p; }

__device__ inline unsigned pk2(float a, float b){
  union { _Float16 h[2]; unsigned u; } x;
  x.h[0] = (_Float16)a; x.h[1] = (_Float16)b; return x.u;
}

// Convert two relu'd D-tiles (A = rows 0..15, B = rows 16..31 of a 32-row slab,
// cols = 16 edges) into one B-frag k-tile (col=lane&15, k=8*(lane>>4)+j).
// D-layout: lane holds (row=(lane>>4)*4+r, col=lane&15).
__device__ inline half8 cvtshuf(f32x4 A, f32x4 B, int lane){
  unsigned pa0 = pk2(A[0], A[1]), pa1 = pk2(A[2], A[3]);
  unsigned pb0 = pk2(B[0], B[1]), pb1 = pk2(B[2], B[3]);
  int e = lane & 15, qh = (lane >> 4) & 1;
  union { unsigned w[4]; half8 h; } r;
#pragma unroll
  for (int t = 0; t < 4; ++t){
    int src = (2*qh + (t>>1))*16 + e;
    unsigned va = __shfl((t&1) ? pa1 : pa0, src);
    unsigned vb = __shfl((t&1) ? pb1 : pb0, src);
    r.w[t] = (lane < 32) ? va : vb;
  }
  return r.h;
}

// ---- weight packing (unchanged frag layout; also valid as W^T A-frags) ----
__device__ inline void packB(const float* W, int Ksrc, int Nn, _Float16* dst, int sig){
  int ns = (Ksrc + 31) >> 5;
  int t = sig / (ns * 64);
  int rem = sig - t * ns * 64;
  int s = rem >> 6;
  int l = rem & 63;
  int col = t * 16 + (l & 15);
  int k0 = s * 32 + ((l >> 4) << 3);
  half8 v;
#pragma unroll
  for (int j = 0; j < 8; ++j){
    int k = k0 + j;
    v[j] = (_Float16)((k < Ksrc) ? W[k * Nn + col] : 0.f);
  }
  *(half8*)(dst + sig * 8) = v;
}

__device__ inline void packW0(const float* W, const float* bias, _Float16* dst, int sig){
  int t = sig >> 6, l = sig & 63;
  int col = t * 16 + (l & 15);
  int k0 = (l >> 4) << 3;
  half8 v;
#pragma unroll
  for (int j = 0; j < 8; ++j){
    int k = k0 + j;
    float x = 0.f;
    if (k < 9) x = W[k * 256 + col];
    else if (k == 9) x = bias[col];
    v[j] = (_Float16)x;
  }
  *(half8*)(dst + sig * 8) = v;
}

__global__ __launch_bounds__(256) void kPrep(const float* pwW0, const float* pwb0,
    const float* pwW1, const float* pwW2,
    const float* fc1W, const float* pw1W, const float* pw2W, const float* postW, const float* outW,
    _Float16* wsh){
  int sig = blockIdx.x * 256 + threadIdx.x;
  if (sig < 1024){ packW0(pwW0, pwb0, wsh + OFF_W0P, sig); return; }
  sig -= 1024;
  if (sig < 8192){ packB(pwW1, 256, 256, wsh + OFF_W1P, sig); return; }
  sig -= 8192;
  if (sig < 1024){ packB(pwW2, 256, 32, wsh + OFF_W2P, sig); return; }
  sig -= 1024;
  int i = sig / 3840;
  int q = sig - i * 3840;
  if (q < 512){ packB(fc1W + i*4096, 128, 32, wsh + OFF_FC1P + i*4096, q); return; }
  q -= 512;
  if (q < 768){ packB(pw1W + i*6144, 96, 64, wsh + OFF_PW1P + i*6144, q); return; }
  q -= 768;
  if (q < 512){ packB(pw2W + i*4096, 64, 64, wsh + OFF_PW2P + i*4096, q); return; }
  q -= 512;
  if (q < 512){ packB(postW + i*8192, 64, 64, wsh + OFF_POSTP + i*8192, q); return; }
  q -= 512;
  if (q < 512){ packB(postW + i*8192 + 4096, 64, 64, wsh + OFF_POSTP + i*8192 + 4096, q); return; }
  q -= 512;
  packB(outW + i*8192, 64, 128, wsh + OFF_OUTP + i*8192, q);
}

// ---- fused pairwise MLP, transposed space: 128 edges/WG, 2 e-tiles/wave ----
__global__ __launch_bounds__(256) void kP(const float* scores, const float* boxes,
    const int* cI, const int* nI, const float* b1, const float* b2,
    const _Float16* W0p, const _Float16* W1p, const _Float16* W2p, _Float16* pfp){
  __shared__ __align__(16) _Float16 sbuf[2][8192];
  __shared__ __align__(16) _Float16 rawp[8192];
  int tid = threadIdx.x;
  int lane = tid & 63, wave = tid >> 6;
  const f32x4 fz = {0.f, 0.f, 0.f, 0.f};

  // prologue: issue W0 + slice0 loads (reg-staged), zero raw buffer
  half8 w0ld[4], s0ld[4];
#pragma unroll
  for (int it = 0; it < 4; ++it){
    w0ld[it] = ldg8(W0p + it*2048 + tid*8);
    s0ld[it] = ldg8(W1p + it*2048 + tid*8);
  }
  {
    half8 z = {0,0,0,0,0,0,0,0};
#pragma unroll
    for (int it = 0; it < 4; ++it) *(half8*)(rawp + it*2048 + tid*8) = z;
  }
  __syncthreads();
  if (tid < 128){
    int e = blockIdx.x*128 + tid;
    int c = cI[e], n = nI[e];
    float cx1 = boxes[c*4+0], cy1 = boxes[c*4+1], cx2 = boxes[c*4+2], cy2 = boxes[c*4+3];
    float nx1 = boxes[n*4+0], ny1 = boxes[n*4+1], nx2 = boxes[n*4+2], ny2 = boxes[n*4+3];
    float cw = cx2-cx1, ch = cy2-cy1, nw = nx2-nx1, nh = ny2-ny1;
    float ca = cw*ch, na = nw*nh;
    float ix = fmaxf(fminf(cx2,nx2) - fmaxf(cx1,nx1), 0.f);
    float iy = fmaxf(fminf(cy2,ny2) - fmaxf(cy1,ny1), 0.f);
    float inter = ix*iy;
    float iou = inter / (ca + na - inter);
    float cs = (cw + ch) * 0.5f;
    float xd = (nx1 + nw*0.5f) - (cx1 + cw*0.5f);
    float yd = (ny1 + nh*0.5f) - (cy1 + ch*0.5f);
    float l2 = sqrtf(xd*xd + yd*yd) / cs;
    float wd = log2f(nw/cw), hd = log2f(nh/ch);
    float ad = log2f(nw/nh) - log2f(cw/ch);
    float rv[10] = {scores[c], scores[n], iou, xd/cs, yd/cs, l2, wd, hd, ad, 1.0f};
    int base = (tid >> 4) * 512;   // e-tile (wave*2+et) region
    int r = tid & 15;
#pragma unroll
    for (int k = 0; k < 10; ++k)
      rawp[base + ((k>>3)*16 + r)*8 + (k&7)] = (_Float16)rv[k];
  }
#pragma unroll
  for (int it = 0; it < 4; ++it){
    *(half8*)(&sbuf[0][0] + it*2048 + tid*8) = w0ld[it];
    *(half8*)(&sbuf[1][0] + it*2048 + tid*8) = s0ld[it];
  }
  __syncthreads();

  // L0: h0T = W0T * rawT  (bias folded via raw[9]=1)
  half8 h0f[2][8];
#pragma unroll
  for (int et = 0; et < 2; ++et){
    half8 braw = *(const half8*)(rawp + ((wave*2+et)*64 + lane)*8);
#pragma unroll
    for (int mp = 0; mp < 8; ++mp){
      f32x4 a = mfma16(*(const half8*)(&sbuf[0][0] + (2*mp)*512   + lane*8), braw, fz);
      f32x4 b = mfma16(*(const half8*)(&sbuf[0][0] + (2*mp+1)*512 + lane*8), braw, fz);
#pragma unroll
      for (int r = 0; r < 4; ++r){ a[r] = fmaxf(a[r], 0.f); b[r] = fmaxf(b[r], 0.f); }
      h0f[et][mp] = cvtshuf(a, b, lane);
    }
  }
  __syncthreads();   // protect sbuf[0] before slice1 is written into it

  // L1 + fused L2: loop over 8 output m-pairs of h1, double-buffered slices
  int q = lane >> 4;
  f32x4 apf[2][2];
  apf[0][0] = fz; apf[0][1] = fz; apf[1][0] = fz; apf[1][1] = fz;
  for (int mp = 0; mp < 8; ++mp){
    const _Float16* cur = &sbuf[(mp+1)&1][0];
    half8 stg[4];
    if (mp < 7){
#pragma unroll
      for (int it = 0; it < 4; ++it)
        stg[it] = ldg8(W1p + (mp+1)*8192 + it*2048 + tid*8);
    }
    f32x4 acc[2][2];
    acc[0][0] = fz; acc[0][1] = fz; acc[1][0] = fz; acc[1][1] = fz;
#pragma unroll
    for (int s = 0; s < 8; ++s){
      half8 A0 = *(const half8*)(cur + s*512       + lane*8);
      half8 A1 = *(const half8*)(cur + (8+s)*512   + lane*8);
#pragma unroll
      for (int et = 0; et < 2; ++et){
        acc[et][0] = mfma16(A0, h0f[et][s], acc[et][0]);
        acc[et][1] = mfma16(A1, h0f[et][s], acc[et][1]);
      }
    }
    f32x4 bv0 = *(const f32x4*)(b1 + mp*32 + q*4);
    f32x4 bv1 = *(const f32x4*)(b1 + mp*32 + 16 + q*4);
    half8 w2a = ldg8(W2p + mp*512 + lane*8);
    half8 w2b = ldg8(W2p + (8+mp)*512 + lane*8);
#pragma unroll
    for (int et = 0; et < 2; ++et){
      f32x4 ra, rb;
#pragma unroll
      for (int r = 0; r < 4; ++r){
        ra[r] = fmaxf(acc[et][0][r] + bv0[r], 0.f);
        rb[r] = fmaxf(acc[et][1][r] + bv1[r], 0.f);
      }
      half8 h1f = cvtshuf(ra, rb, lane);
      apf[et][0] = mfma16(w2a, h1f, apf[et][0]);
      apf[et][1] = mfma16(w2b, h1f, apf[et][1]);
    }
    if (mp < 7){
      _Float16* nxt = &sbuf[mp&1][0];
#pragma unroll
      for (int it = 0; it < 4; ++it)
        *(half8*)(nxt + it*2048 + tid*8) = stg[it];
    }
    __syncthreads();
  }
  // epilogue: pf = relu(pfT + b2) -> frag -> store
  f32x4 c0 = *(const f32x4*)(b2 + q*4);
  f32x4 c1 = *(const f32x4*)(b2 + 16 + q*4);
#pragma unroll
  for (int et = 0; et < 2; ++et){
    f32x4 ra, rb;
#pragma unroll
    for (int r = 0; r < 4; ++r){
      ra[r] = fmaxf(apf[et][0][r] + c0[r], 0.f);
      rb[r] = fmaxf(apf[et][1][r] + c1[r], 0.f);
    }
    half8 pf = cvtshuf(ra, rb, lane);
    *(half8*)(pfp + (blockIdx.x*8 + wave*2 + et)*512 + lane*8) = pf;
  }
}

// ---- initial f1 (transposed), 16 dets per wave ----
__global__ __launch_bounds__(64) void kF1(const float* detF, const _Float16* fc1p,
    const float* fb, _Float16* f1G){
  int lane = threadIdx.x & 63;
  int q = lane >> 4, e = lane & 15;
  int det = blockIdx.x * 16 + e;
  const f32x4 fz = {0.f, 0.f, 0.f, 0.f};
  half8 ff[4];
#pragma unroll
  for (int s = 0; s < 4; ++s){
    const float* p = detF + det*128 + s*32 + q*8;
    f32x4 x0 = *(const f32x4*)(p);
    f32x4 x1 = *(const f32x4*)(p + 4);
    union { unsigned w[4]; half8 h; } u;
    u.w[0] = pk2(x0[0], x0[1]); u.w[1] = pk2(x0[2], x0[3]);
    u.w[2] = pk2(x1[0], x1[1]); u.w[3] = pk2(x1[2], x1[3]);
    ff[s] = u.h;
  }
#pragma unroll
  for (int m = 0; m < 2; ++m){
    f32x4 a = fz;
#pragma unroll
    for (int s = 0; s < 4; ++s)
      a = mfma16(ldg8(fc1p + (m*4+s)*512 + lane*8), ff[s], a);
    f32x4 bv = *(const f32x4*)(fb + m*16 + q*4);
    unsigned u0 = pk2(fmaxf(a[0]+bv[0],0.f), fmaxf(a[1]+bv[1],0.f));
    unsigned u1 = pk2(fmaxf(a[2]+bv[2],0.f), fmaxf(a[3]+bv[3],0.f));
    *(unsigned*)(f1G + det*32 + m*16 + q*4)     = u0;
    *(unsigned*)(f1G + det*32 + m*16 + q*4 + 2) = u1;
  }
}

// ---- per-block edge MLP + segment max, weights in VGPRs, no LDS ----
__global__ __launch_bounds__(256) void kB2(const _Float16* pfp, const _Float16* f1G, _Float16* poolG,
    const int* cI, const int* nI, const _Float16* pw1p, const _Float16* pw2p,
    const float* bb1, const float* bb2){
  int tid = threadIdx.x, lane = tid & 63, wave = tid >> 6;
  int q = lane >> 4, e = lane & 15;
  const f32x4 fz = {0.f, 0.f, 0.f, 0.f};
  half8 aW1[4][3], aW2[4][2];
  f32x4 b1v[4], b2v[4];
#pragma unroll
  for (int m = 0; m < 4; ++m){
#pragma unroll
    for (int k = 0; k < 3; ++k) aW1[m][k] = ldg8(pw1p + (m*3+k)*512 + lane*8);
#pragma unroll
    for (int k = 0; k < 2; ++k) aW2[m][k] = ldg8(pw2p + (m*2+k)*512 + lane*8);
    b1v[m] = *(const f32x4*)(bb1 + m*16 + q*4);
    b2v[m] = *(const f32x4*)(bb2 + m*16 + q*4);
  }
  for (int dd = 0; dd < 4; ++dd){
    int det = blockIdx.x*16 + wave*4 + dd;
    f32x4 pmax[4];
#pragma unroll
    for (int m = 0; m < 4; ++m) pmax[m] = fz;
#pragma unroll
    for (int et = 0; et < 4; ++et){
      int ebase = det*64 + et*16;
      half8 Bpf = ldg8(pfp + (det*4+et)*512 + lane*8);
      int c = cI[ebase + e], n = nI[ebase + e];
      half8 Bc = ldg8(f1G + c*32 + q*8);
      half8 Bn = ldg8(f1G + n*32 + q*8);
      f32x4 acc[4];
#pragma unroll
      for (int m = 0; m < 4; ++m){
        acc[m] = mfma16(aW1[m][0], Bpf, fz);
        acc[m] = mfma16(aW1[m][1], Bc, acc[m]);
        acc[m] = mfma16(aW1[m][2], Bn, acc[m]);
      }
      f32x4 r0, r1, r2, r3;
#pragma unroll
      for (int r = 0; r < 4; ++r){
        r0[r] = fmaxf(acc[0][r] + b1v[0][r], 0.f);
        r1[r] = fmaxf(acc[1][r] + b1v[1][r], 0.f);
        r2[r] = fmaxf(acc[2][r] + b1v[2][r], 0.f);
        r3[r] = fmaxf(acc[3][r] + b1v[3][r], 0.f);
      }
      half8 h1a = cvtshuf(r0, r1, lane);
      half8 h1b = cvtshuf(r2, r3, lane);
#pragma unroll
      for (int m = 0; m < 4; ++m){
        f32x4 a2 = mfma16(aW2[m][0], h1a, fz);
        a2 = mfma16(aW2[m][1], h1b, a2);
#pragma unroll
        for (int r = 0; r < 4; ++r)
          pmax[m][r] = fmaxf(pmax[m][r], fmaxf(a2[r] + b2v[m][r], 0.f));
      }
    }
#pragma unroll
    for (int m = 0; m < 4; ++m){
#pragma unroll
      for (int r = 0; r < 4; ++r){
        float v = pmax[m][r];
        v = fmaxf(v, __shfl_xor(v, 1));
        v = fmaxf(v, __shfl_xor(v, 2));
        v = fmaxf(v, __shfl_xor(v, 4));
        v = fmaxf(v, __shfl_xor(v, 8));
        pmax[m][r] = v;
      }
      if (e == 0) *(unsigned*)(poolG + det*64 + m*16 + q*4)     = pk2(pmax[m][0], pmax[m][1]);
      if (e == 1) *(unsigned*)(poolG + det*64 + m*16 + q*4 + 2) = pk2(pmax[m][2], pmax[m][3]);
    }
  }
}

// ---- post MLPs + residual + fused next-block f1, transposed, 16 dets/wave ----
__global__ __launch_bounds__(64) void kB3(const _Float16* poolG, const float* fin, float* fout,
    _Float16* f1G, const _Float16* post0p, const _Float16* post1p, const _Float16* outp,
    const _Float16* fc1pn, const float* pb0, const float* pb1, const float* ob,
    const float* fbn, int doF1){
  int lane = threadIdx.x & 63;
  int q = lane >> 4, e = lane & 15;
  int det = blockIdx.x * 16 + e;
  const f32x4 fz = {0.f, 0.f, 0.f, 0.f};
  half8 Bp0 = ldg8(poolG + det*64 + q*8);
  half8 Bp1 = ldg8(poolG + det*64 + 32 + q*8);
  // p1 = relu(post0T * poolT + b)
  f32x4 t0[4];
#pragma unroll
  for (int m = 0; m < 4; ++m){
    f32x4 a = mfma16(ldg8(post0p + (m*2)*512   + lane*8), Bp0, fz);
    a = mfma16(ldg8(post0p + (m*2+1)*512 + lane*8), Bp1, a);
    f32x4 bv = *(const f32x4*)(pb0 + m*16 + q*4);
#pragma unroll
    for (int r = 0; r < 4; ++r) t0[m][r] = fmaxf(a[r] + bv[r], 0.f);
  }
  half8 p1a = cvtshuf(t0[0], t0[1], lane);
  half8 p1b = cvtshuf(t0[2], t0[3], lane);
  // p2 = relu(post1T * p1T + b)
#pragma unroll
  for (int m = 0; m < 4; ++m){
    f32x4 a = mfma16(ldg8(post1p + (m*2)*512   + lane*8), p1a, fz);
    a = mfma16(ldg8(post1p + (m*2+1)*512 + lane*8), p1b, a);
    f32x4 bv = *(const f32x4*)(pb1 + m*16 + q*4);
#pragma unroll
    for (int r = 0; r < 4; ++r) t0[m][r] = fmaxf(a[r] + bv[r], 0.f);
  }
  half8 p2a = cvtshuf(t0[0], t0[1], lane);
  half8 p2b = cvtshuf(t0[2], t0[3], lane);
  // fnew = relu(f + outT * p2T + b)
  f32x4 fr[8];
#pragma unroll
  for (int m = 0; m < 8; ++m){
    f32x4 a = mfma16(ldg8(outp + (m*2)*512   + lane*8), p2a, fz);
    a = mfma16(ldg8(outp + (m*2+1)*512 + lane*8), p2b, a);
    f32x4 bv = *(const f32x4*)(ob + m*16 + q*4);
    f32x4 fv = *(const f32x4*)(fin + det*128 + m*16 + q*4);
#pragma unroll
    for (int r = 0; r < 4; ++r) fr[m][r] = fmaxf(fv[r] + a[r] + bv[r], 0.f);
    *(f32x4*)(fout + det*128 + m*16 + q*4) = fr[m];
  }
  if (doF1){
    half8 ff[4];
#pragma unroll
    for (int s = 0; s < 4; ++s) ff[s] = cvtshuf(fr[2*s], fr[2*s+1], lane);
#pragma unroll
    for (int m = 0; m < 2; ++m){
      f32x4 a = fz;
#pragma unroll
      for (int s = 0; s < 4; ++s)
        a = mfma16(ldg8(fc1pn + (m*4+s)*512 + lane*8), ff[s], a);
      f32x4 bv = *(const f32x4*)(fbn + m*16 + q*4);
      unsigned u0 = pk2(fmaxf(a[0]+bv[0],0.f), fmaxf(a[1]+bv[1],0.f));
      unsigned u1 = pk2(fmaxf(a[2]+bv[2],0.f), fmaxf(a[3]+bv[3],0.f));
      *(unsigned*)(f1G + det*32 + m*16 + q*4)     = u0;
      *(unsigned*)(f1G + det*32 + m*16 + q*4 + 2) = u1;
    }
  }
}

extern "C" void kernel_launch(void* const* d_in, const int* in_sizes, int n_in,
                              void* d_out, int out_size, void* d_ws, size_t ws_size,
                              hipStream_t stream){
  const float* detScores   = (const float*)d_in[0];
  const float* dtBoxes     = (const float*)d_in[1];
  const float* detFeatures = (const float*)d_in[2];
  const int*   cI          = (const int*)d_in[3];
  const int*   nI          = (const int*)d_in[4];
  const float* pwW0 = (const float*)d_in[5];
  const float* pwb0 = (const float*)d_in[6];
  const float* pwW1 = (const float*)d_in[7];
  const float* pwb1 = (const float*)d_in[8];
  const float* pwW2 = (const float*)d_in[9];
  const float* pwb2 = (const float*)d_in[10];
  const float* fc1W = (const float*)d_in[11];
  const float* fc1b = (const float*)d_in[12];
  const float* pw1W = (const float*)d_in[13];
  const float* pw1b = (const float*)d_in[14];
  const float* pw2W = (const float*)d_in[15];
  const float* pw2b = (const float*)d_in[16];
  const float* postW = (const float*)d_in[17];
  const float* postb = (const float*)d_in[18];
  const float* outW  = (const float*)d_in[19];
  const float* outb  = (const float*)d_in[20];

  _Float16* wsh  = (_Float16*)d_ws;
  float*    fbuf = (float*)((char*)d_ws + OFF_FBUF_BYTES);
  _Float16* f1G   = wsh + OFF_F1;
  _Float16* poolG = wsh + OFF_POOL;
  _Float16* pfp   = wsh + OFF_PFP;

  kPrep<<<160, 256, 0, stream>>>(pwW0, pwb0, pwW1, pwW2, fc1W, pw1W, pw2W, postW, outW, wsh);
  kF1<<<512, 64, 0, stream>>>(detFeatures, wsh + OFF_FC1P, fc1b, f1G);
  kP<<<4096, 256, 0, stream>>>(detScores, dtBoxes, cI, nI, pwb1, pwb2,
      wsh + OFF_W0P, wsh + OFF_W1P, wsh + OFF_W2P, pfp);

  for (int i = 0; i < 8; ++i){
    int last = (i == 7);
    kB2<<<512, 256, 0, stream>>>(pfp, f1G, poolG, cI, nI,
        wsh + OFF_PW1P + i*6144, wsh + OFF_PW2P + i*4096, pw1b + i*64, pw2b + i*64);
    kB3<<<512, 64, 0, stream>>>(poolG, (i == 0) ? detFeatures : fbuf,
        last ? (float*)d_out : fbuf, f1G,
        wsh + OFF_POSTP + i*8192, wsh + OFF_POSTP + i*8192 + 4096, wsh + OFF_OUTP + i*8192,
        wsh + OFF_FC1P + ((i+1) & 7)*4096,
        postb + i*128, postb + i*128 + 64, outb + i*128,
        fc1b + ((i+1) & 7)*32, last ? 0 : 1);
  }
}

// Round 3
// 307.497 us; speedup vs baseline: 1.5679x; 1.1879x over previous
//
#include <hip/hip_runtime.h>
#include <hip/hip_bf16.h>

typedef _Float16 half8 __attribute__((ext_vector_type(8)));
typedef float f32x4 __attribute__((ext_vector_type(4)));

#define N_DETS 8192

// ---- workspace layout (offsets in _Float16 units unless noted) ----
#define OFF_W0P   0          // 16 frags x 512 (k=9 row holds pw_b0)
#define OFF_W1P   8192       // 16x8x512
#define OFF_W2P   73728      // 2x8x512
#define OFF_FC1P  81920      // 8 x (2x4x512)
#define OFF_PW1P  114688     // 8 x (4x3x512)
#define OFF_PW2P  163840     // 8 x (4x2x512)
#define OFF_POSTP 196608     // 8 x 2 x (4x2x512)
#define OFF_OUTP  262144     // 8 x (8x2x512)
#define OFF_F1A   327680     // 8192x32 f16 (pi-frag layout), ping
#define OFF_F1B   589824     // 8192x32 f16, pong
#define OFF_PFP   1114112    // 32768 edge-tiles x 512 (pi-frags of pairFeatures)
#define OFF_FBUF_BYTES 35782656  // f32 [8192][128]

// pi slot map: physical slot (g = lane>>4, j) <-> logical k = ((j>>2)<<4) + g*4 + (j&3)
// Both MFMA operands use the same map, so products pair correctly, and the D-tile
// pair (rows 0..15, 16..31) converts to a B-frag with pure in-lane packing.

__device__ inline f32x4 mfma16(half8 a, half8 b, f32x4 c){
  return __builtin_amdgcn_mfma_f32_16x16x32_f16(a, b, c, 0, 0, 0);
}
__device__ inline half8 ldg8(const _Float16* p){ return *(const half8*)p; }

__device__ inline unsigned pk2(float a, float b){
  union { _Float16 h[2]; unsigned u; } x;
  x.h[0] = (_Float16)a; x.h[1] = (_Float16)b; return x.u;
}

// D-pair -> B-frag under pi: slots 0-3 = A rows g*4+r, slots 4-7 = B rows 16+g*4+r.
__device__ inline half8 cvtpack(f32x4 A, f32x4 B){
  union { unsigned w[4]; half8 h; } r;
  r.w[0] = pk2(A[0], A[1]); r.w[1] = pk2(A[2], A[3]);
  r.w[2] = pk2(B[0], B[1]); r.w[3] = pk2(B[2], B[3]);
  return r.h;
}

// ---- weight packing in pi order (valid as A-frags of W^T) ----
__device__ inline void packB(const float* W, int Ksrc, int Nn, _Float16* dst, int sig){
  int ns = (Ksrc + 31) >> 5;
  int t = sig / (ns * 64);
  int rem = sig - t * ns * 64;
  int s = rem >> 6;
  int l = rem & 63;
  int col = t * 16 + (l & 15);
  int g = l >> 4;
  half8 v;
#pragma unroll
  for (int j = 0; j < 8; ++j){
    int k = s*32 + ((j>>2)<<4) + g*4 + (j&3);
    v[j] = (_Float16)((k < Ksrc) ? W[k * Nn + col] : 0.f);
  }
  *(half8*)(dst + sig * 8) = v;
}

__device__ inline void packW0(const float* W, const float* bias, _Float16* dst, int sig){
  int t = sig >> 6, l = sig & 63;
  int col = t * 16 + (l & 15);
  int g = l >> 4;
  half8 v;
#pragma unroll
  for (int j = 0; j < 8; ++j){
    int k = ((j>>2)<<4) + g*4 + (j&3);
    float x = 0.f;
    if (k < 9) x = W[k * 256 + col];
    else if (k == 9) x = bias[col];
    v[j] = (_Float16)x;
  }
  *(half8*)(dst + sig * 8) = v;
}

__global__ __launch_bounds__(256) void kPrep(const float* pwW0, const float* pwb0,
    const float* pwW1, const float* pwW2,
    const float* fc1W, const float* pw1W, const float* pw2W, const float* postW, const float* outW,
    _Float16* wsh){
  int sig = blockIdx.x * 256 + threadIdx.x;
  if (sig < 1024){ packW0(pwW0, pwb0, wsh + OFF_W0P, sig); return; }
  sig -= 1024;
  if (sig < 8192){ packB(pwW1, 256, 256, wsh + OFF_W1P, sig); return; }
  sig -= 8192;
  if (sig < 1024){ packB(pwW2, 256, 32, wsh + OFF_W2P, sig); return; }
  sig -= 1024;
  int i = sig / 3840;
  int q = sig - i * 3840;
  if (q < 512){ packB(fc1W + i*4096, 128, 32, wsh + OFF_FC1P + i*4096, q); return; }
  q -= 512;
  if (q < 768){ packB(pw1W + i*6144, 96, 64, wsh + OFF_PW1P + i*6144, q); return; }
  q -= 768;
  if (q < 512){ packB(pw2W + i*4096, 64, 64, wsh + OFF_PW2P + i*4096, q); return; }
  q -= 512;
  if (q < 512){ packB(postW + i*8192, 64, 64, wsh + OFF_POSTP + i*8192, q); return; }
  q -= 512;
  if (q < 512){ packB(postW + i*8192 + 4096, 64, 64, wsh + OFF_POSTP + i*8192 + 4096, q); return; }
  q -= 512;
  packB(outW + i*8192, 64, 128, wsh + OFF_OUTP + i*8192, q);
}

// ---- fused pairwise MLP, transposed space: 128 edges/WG, 2 e-tiles/wave ----
__global__ __launch_bounds__(256) void kP(const float* scores, const float* boxes,
    const int* cI, const int* nI, const float* b1, const float* b2,
    const _Float16* W0p, const _Float16* W1p, const _Float16* W2p, _Float16* pfp){
  __shared__ __align__(16) _Float16 sbuf[2][8192];
  __shared__ __align__(16) _Float16 rawp[8192];
  int tid = threadIdx.x;
  int lane = tid & 63, wave = tid >> 6;
  const f32x4 fz = {0.f, 0.f, 0.f, 0.f};

  // prologue: issue W0 + slice0 loads (reg-staged), zero raw buffer
  half8 w0ld[4], s0ld[4];
#pragma unroll
  for (int it = 0; it < 4; ++it){
    w0ld[it] = ldg8(W0p + it*2048 + tid*8);
    s0ld[it] = ldg8(W1p + it*2048 + tid*8);
  }
  {
    half8 z = {0,0,0,0,0,0,0,0};
#pragma unroll
    for (int it = 0; it < 4; ++it) *(half8*)(rawp + it*2048 + tid*8) = z;
  }
  __syncthreads();
  if (tid < 128){
    int e = blockIdx.x*128 + tid;
    int c = cI[e], n = nI[e];
    float cx1 = boxes[c*4+0], cy1 = boxes[c*4+1], cx2 = boxes[c*4+2], cy2 = boxes[c*4+3];
    float nx1 = boxes[n*4+0], ny1 = boxes[n*4+1], nx2 = boxes[n*4+2], ny2 = boxes[n*4+3];
    float cw = cx2-cx1, ch = cy2-cy1, nw = nx2-nx1, nh = ny2-ny1;
    float ca = cw*ch, na = nw*nh;
    float ix = fmaxf(fminf(cx2,nx2) - fmaxf(cx1,nx1), 0.f);
    float iy = fmaxf(fminf(cy2,ny2) - fmaxf(cy1,ny1), 0.f);
    float inter = ix*iy;
    float iou = inter / (ca + na - inter);
    float cs = (cw + ch) * 0.5f;
    float xd = (nx1 + nw*0.5f) - (cx1 + cw*0.5f);
    float yd = (ny1 + nh*0.5f) - (cy1 + ch*0.5f);
    float l2 = sqrtf(xd*xd + yd*yd) / cs;
    float wd = log2f(nw/cw), hd = log2f(nh/ch);
    float ad = log2f(nw/nh) - log2f(cw/ch);
    float rv[10] = {scores[c], scores[n], iou, xd/cs, yd/cs, l2, wd, hd, ad, 1.0f};
    int base = (tid >> 4) * 512;   // e-tile region
    int r = tid & 15;
#pragma unroll
    for (int k = 0; k < 10; ++k)
      rawp[base + (((k>>2)&3)*16 + r)*8 + (k&3)] = (_Float16)rv[k];   // pi position
  }
#pragma unroll
  for (int it = 0; it < 4; ++it){
    *(half8*)(&sbuf[0][0] + it*2048 + tid*8) = w0ld[it];
    *(half8*)(&sbuf[1][0] + it*2048 + tid*8) = s0ld[it];
  }
  __syncthreads();

  // L0: h0T = W0T * rawT  (bias folded via raw[9]=1)
  half8 h0f[2][8];
#pragma unroll
  for (int et = 0; et < 2; ++et){
    half8 braw = *(const half8*)(rawp + ((wave*2+et)*64 + lane)*8);
#pragma unroll
    for (int mp = 0; mp < 8; ++mp){
      f32x4 a = mfma16(*(const half8*)(&sbuf[0][0] + (2*mp)*512   + lane*8), braw, fz);
      f32x4 b = mfma16(*(const half8*)(&sbuf[0][0] + (2*mp+1)*512 + lane*8), braw, fz);
#pragma unroll
      for (int r = 0; r < 4; ++r){ a[r] = fmaxf(a[r], 0.f); b[r] = fmaxf(b[r], 0.f); }
      h0f[et][mp] = cvtpack(a, b);
    }
  }
  __syncthreads();   // protect sbuf[0] before slice1 is written into it

  // L1 + fused L2: loop over 8 output m-pairs of h1, double-buffered slices
  int q = lane >> 4;
  f32x4 apf[2][2];
  apf[0][0] = fz; apf[0][1] = fz; apf[1][0] = fz; apf[1][1] = fz;
  for (int mp = 0; mp < 8; ++mp){
    const _Float16* cur = &sbuf[(mp+1)&1][0];
    half8 stg[4];
    if (mp < 7){
#pragma unroll
      for (int it = 0; it < 4; ++it)
        stg[it] = ldg8(W1p + (mp+1)*8192 + it*2048 + tid*8);
    }
    f32x4 acc[2][2];
    acc[0][0] = fz; acc[0][1] = fz; acc[1][0] = fz; acc[1][1] = fz;
#pragma unroll
    for (int s = 0; s < 8; ++s){
      half8 A0 = *(const half8*)(cur + s*512       + lane*8);
      half8 A1 = *(const half8*)(cur + (8+s)*512   + lane*8);
#pragma unroll
      for (int et = 0; et < 2; ++et){
        acc[et][0] = mfma16(A0, h0f[et][s], acc[et][0]);
        acc[et][1] = mfma16(A1, h0f[et][s], acc[et][1]);
      }
    }
    f32x4 bv0 = *(const f32x4*)(b1 + mp*32 + q*4);
    f32x4 bv1 = *(const f32x4*)(b1 + mp*32 + 16 + q*4);
    half8 w2a = ldg8(W2p + mp*512 + lane*8);
    half8 w2b = ldg8(W2p + (8+mp)*512 + lane*8);
#pragma unroll
    for (int et = 0; et < 2; ++et){
      f32x4 ra, rb;
#pragma unroll
      for (int r = 0; r < 4; ++r){
        ra[r] = fmaxf(acc[et][0][r] + bv0[r], 0.f);
        rb[r] = fmaxf(acc[et][1][r] + bv1[r], 0.f);
      }
      half8 h1f = cvtpack(ra, rb);
      apf[et][0] = mfma16(w2a, h1f, apf[et][0]);
      apf[et][1] = mfma16(w2b, h1f, apf[et][1]);
    }
    if (mp < 7){
      _Float16* nxt = &sbuf[mp&1][0];
#pragma unroll
      for (int it = 0; it < 4; ++it)
        *(half8*)(nxt + it*2048 + tid*8) = stg[it];
    }
    __syncthreads();
  }
  // epilogue: pf = relu(pfT + b2) -> pi-frag -> store
  f32x4 c0 = *(const f32x4*)(b2 + q*4);
  f32x4 c1 = *(const f32x4*)(b2 + 16 + q*4);
#pragma unroll
  for (int et = 0; et < 2; ++et){
    f32x4 ra, rb;
#pragma unroll
    for (int r = 0; r < 4; ++r){
      ra[r] = fmaxf(apf[et][0][r] + c0[r], 0.f);
      rb[r] = fmaxf(apf[et][1][r] + c1[r], 0.f);
    }
    half8 pf = cvtpack(ra, rb);
    *(half8*)(pfp + (blockIdx.x*8 + wave*2 + et)*512 + lane*8) = pf;
  }
}

// ---- initial f1 (transposed), 16 dets per wave, 4 waves/WG ----
__global__ __launch_bounds__(256) void kF1(const float* detF, const _Float16* fc1p,
    const float* fb, _Float16* f1G){
  int lane = threadIdx.x & 63, wave = threadIdx.x >> 6;
  int q = lane >> 4, e = lane & 15;
  int det = (blockIdx.x * 4 + wave) * 16 + e;
  const f32x4 fz = {0.f, 0.f, 0.f, 0.f};
  half8 ff[4];
#pragma unroll
  for (int s = 0; s < 4; ++s){
    const float* p = detF + det*128 + s*32 + q*4;
    f32x4 x0 = *(const f32x4*)(p);
    f32x4 x1 = *(const f32x4*)(p + 16);
    union { unsigned w[4]; half8 h; } u;
    u.w[0] = pk2(x0[0], x0[1]); u.w[1] = pk2(x0[2], x0[3]);
    u.w[2] = pk2(x1[0], x1[1]); u.w[3] = pk2(x1[2], x1[3]);
    ff[s] = u.h;
  }
#pragma unroll
  for (int m = 0; m < 2; ++m){
    f32x4 a = fz;
#pragma unroll
    for (int s = 0; s < 4; ++s)
      a = mfma16(ldg8(fc1p + (m*4+s)*512 + lane*8), ff[s], a);
    f32x4 bv = *(const f32x4*)(fb + m*16 + q*4);
    unsigned u0 = pk2(fmaxf(a[0]+bv[0],0.f), fmaxf(a[1]+bv[1],0.f));
    unsigned u1 = pk2(fmaxf(a[2]+bv[2],0.f), fmaxf(a[3]+bv[3],0.f));
    *(unsigned*)(f1G + det*32 + q*8 + m*4)     = u0;
    *(unsigned*)(f1G + det*32 + q*8 + m*4 + 2) = u1;
  }
}

// ---- one graph block: edge MLP + segment max + post MLPs + residual + next f1 ----
__global__ __launch_bounds__(256) void kBlk(const _Float16* pfp, const _Float16* f1in,
    _Float16* f1out, const int* nI, const _Float16* pw1p, const _Float16* pw2p,
    const _Float16* post0p, const _Float16* post1p, const _Float16* outp, const _Float16* fc1pn,
    const float* bb1, const float* bb2, const float* pb0, const float* pb1, const float* ob,
    const float* fbn, const float* fin, float* fout, int doF1){
  __shared__ __align__(16) _Float16 poolS[1024];  // [2 halves][16 dets][32 halfs]
  int tid = threadIdx.x, lane = tid & 63, wave = tid >> 6;
  int q = lane >> 4, e = lane & 15;
  int base = blockIdx.x * 16;
  const f32x4 fz = {0.f, 0.f, 0.f, 0.f};

  // ---- phase A: edge MLP + pooling (wave handles 4 dets, weights in VGPRs) ----
  half8 aW1[4][3], aW2[4][2];
  f32x4 b1v[4], b2v[4];
#pragma unroll
  for (int m = 0; m < 4; ++m){
#pragma unroll
    for (int k = 0; k < 3; ++k) aW1[m][k] = ldg8(pw1p + (m*3+k)*512 + lane*8);
#pragma unroll
    for (int k = 0; k < 2; ++k) aW2[m][k] = ldg8(pw2p + (m*2+k)*512 + lane*8);
    b1v[m] = *(const f32x4*)(bb1 + m*16 + q*4);
    b2v[m] = *(const f32x4*)(bb2 + m*16 + q*4);
  }
  for (int dd = 0; dd < 4; ++dd){
    int d = wave*4 + dd;
    int det = base + d;
    half8 Bc = ldg8(f1in + det*32 + q*8);   // cIdxs == det for every edge of det
    f32x4 pmax[4];
#pragma unroll
    for (int m = 0; m < 4; ++m) pmax[m] = fz;
#pragma unroll
    for (int et = 0; et < 4; ++et){
      half8 Bpf = ldg8(pfp + (det*4+et)*512 + lane*8);
      int n = nI[det*64 + et*16 + e];
      half8 Bn = ldg8(f1in + n*32 + q*8);
      f32x4 acc[4];
#pragma unroll
      for (int m = 0; m < 4; ++m){
        acc[m] = mfma16(aW1[m][0], Bpf, fz);
        acc[m] = mfma16(aW1[m][1], Bc, acc[m]);
        acc[m] = mfma16(aW1[m][2], Bn, acc[m]);
      }
      f32x4 r0, r1, r2, r3;
#pragma unroll
      for (int r = 0; r < 4; ++r){
        r0[r] = fmaxf(acc[0][r] + b1v[0][r], 0.f);
        r1[r] = fmaxf(acc[1][r] + b1v[1][r], 0.f);
        r2[r] = fmaxf(acc[2][r] + b1v[2][r], 0.f);
        r3[r] = fmaxf(acc[3][r] + b1v[3][r], 0.f);
      }
      half8 h1a = cvtpack(r0, r1);
      half8 h1b = cvtpack(r2, r3);
#pragma unroll
      for (int m = 0; m < 4; ++m){
        f32x4 a2 = mfma16(aW2[m][0], h1a, fz);
        a2 = mfma16(aW2[m][1], h1b, a2);
#pragma unroll
        for (int r = 0; r < 4; ++r)
          pmax[m][r] = fmaxf(pmax[m][r], fmaxf(a2[r] + b2v[m][r], 0.f));
      }
    }
#pragma unroll
    for (int m = 0; m < 4; ++m){
#pragma unroll
      for (int r = 0; r < 4; ++r){
        float v = pmax[m][r];
        v = fmaxf(v, __shfl_xor(v, 1));
        v = fmaxf(v, __shfl_xor(v, 2));
        v = fmaxf(v, __shfl_xor(v, 4));
        v = fmaxf(v, __shfl_xor(v, 8));
        pmax[m][r] = v;
      }
    }
    if (e == 0){
      union { unsigned w[4]; half8 h; } u0, u1;
      u0.w[0] = pk2(pmax[0][0], pmax[0][1]); u0.w[1] = pk2(pmax[0][2], pmax[0][3]);
      u0.w[2] = pk2(pmax[1][0], pmax[1][1]); u0.w[3] = pk2(pmax[1][2], pmax[1][3]);
      u1.w[0] = pk2(pmax[2][0], pmax[2][1]); u1.w[1] = pk2(pmax[2][2], pmax[2][3]);
      u1.w[2] = pk2(pmax[3][0], pmax[3][1]); u1.w[3] = pk2(pmax[3][2], pmax[3][3]);
      *(half8*)(poolS + d*32 + q*8)       = u0.h;   // k 0..31
      *(half8*)(poolS + 512 + d*32 + q*8) = u1.h;   // k 32..63
    }
  }
  __syncthreads();

  // ---- phase B: post MLPs + residual + next f1 (dets are frag cols) ----
  half8 Bp0 = *(const half8*)(poolS + e*32 + q*8);
  half8 Bp1 = *(const half8*)(poolS + 512 + e*32 + q*8);
  int det = base + e;
  f32x4 t0[4];
#pragma unroll
  for (int m = 0; m < 4; ++m){
    f32x4 a = mfma16(ldg8(post0p + (m*2)*512   + lane*8), Bp0, fz);
    a = mfma16(ldg8(post0p + (m*2+1)*512 + lane*8), Bp1, a);
    f32x4 bv = *(const f32x4*)(pb0 + m*16 + q*4);
#pragma unroll
    for (int r = 0; r < 4; ++r) t0[m][r] = fmaxf(a[r] + bv[r], 0.f);
  }
  half8 p1a = cvtpack(t0[0], t0[1]);
  half8 p1b = cvtpack(t0[2], t0[3]);
#pragma unroll
  for (int m = 0; m < 4; ++m){
    f32x4 a = mfma16(ldg8(post1p + (m*2)*512   + lane*8), p1a, fz);
    a = mfma16(ldg8(post1p + (m*2+1)*512 + lane*8), p1b, a);
    f32x4 bv = *(const f32x4*)(pb1 + m*16 + q*4);
#pragma unroll
    for (int r = 0; r < 4; ++r) t0[m][r] = fmaxf(a[r] + bv[r], 0.f);
  }
  half8 p2a = cvtpack(t0[0], t0[1]);
  half8 p2b = cvtpack(t0[2], t0[3]);
  f32x4 fr[8];
#pragma unroll
  for (int m = 0; m < 8; ++m){
    f32x4 a = mfma16(ldg8(outp + (m*2)*512   + lane*8), p2a, fz);
    a = mfma16(ldg8(outp + (m*2+1)*512 + lane*8), p2b, a);
    f32x4 bv = *(const f32x4*)(ob + m*16 + q*4);
    f32x4 fv = *(const f32x4*)(fin + det*128 + m*16 + q*4);
#pragma unroll
    for (int r = 0; r < 4; ++r) fr[m][r] = fmaxf(fv[r] + a[r] + bv[r], 0.f);
  }
#pragma unroll
  for (int mm = 0; mm < 2; ++mm){
    int m = wave*2 + mm;
    *(f32x4*)(fout + det*128 + m*16 + q*4) = fr[m];
  }
  if (doF1 && wave == 0){
    half8 ff[4];
#pragma unroll
    for (int s = 0; s < 4; ++s) ff[s] = cvtpack(fr[2*s], fr[2*s+1]);
#pragma unroll
    for (int m = 0; m < 2; ++m){
      f32x4 a = fz;
#pragma unroll
      for (int s = 0; s < 4; ++s)
        a = mfma16(ldg8(fc1pn + (m*4+s)*512 + lane*8), ff[s], a);
      f32x4 bv = *(const f32x4*)(fbn + m*16 + q*4);
      unsigned u0 = pk2(fmaxf(a[0]+bv[0],0.f), fmaxf(a[1]+bv[1],0.f));
      unsigned u1 = pk2(fmaxf(a[2]+bv[2],0.f), fmaxf(a[3]+bv[3],0.f));
      *(unsigned*)(f1out + det*32 + q*8 + m*4)     = u0;
      *(unsigned*)(f1out + det*32 + q*8 + m*4 + 2) = u1;
    }
  }
}

extern "C" void kernel_launch(void* const* d_in, const int* in_sizes, int n_in,
                              void* d_out, int out_size, void* d_ws, size_t ws_size,
                              hipStream_t stream){
  const float* detScores   = (const float*)d_in[0];
  const float* dtBoxes     = (const float*)d_in[1];
  const float* detFeatures = (const float*)d_in[2];
  const int*   cI          = (const int*)d_in[3];
  const int*   nI          = (const int*)d_in[4];
  const float* pwW0 = (const float*)d_in[5];
  const float* pwb0 = (const float*)d_in[6];
  const float* pwW1 = (const float*)d_in[7];
  const float* pwb1 = (const float*)d_in[8];
  const float* pwW2 = (const float*)d_in[9];
  const float* pwb2 = (const float*)d_in[10];
  const float* fc1W = (const float*)d_in[11];
  const float* fc1b = (const float*)d_in[12];
  const float* pw1W = (const float*)d_in[13];
  const float* pw1b = (const float*)d_in[14];
  const float* pw2W = (const float*)d_in[15];
  const float* pw2b = (const float*)d_in[16];
  const float* postW = (const float*)d_in[17];
  const float* postb = (const float*)d_in[18];
  const float* outW  = (const float*)d_in[19];
  const float* outb  = (const float*)d_in[20];

  _Float16* wsh  = (_Float16*)d_ws;
  float*    fbuf = (float*)((char*)d_ws + OFF_FBUF_BYTES);
  _Float16* f1A  = wsh + OFF_F1A;
  _Float16* f1B  = wsh + OFF_F1B;
  _Float16* pfp  = wsh + OFF_PFP;

  kPrep<<<160, 256, 0, stream>>>(pwW0, pwb0, pwW1, pwW2, fc1W, pw1W, pw2W, postW, outW, wsh);
  kF1<<<128, 256, 0, stream>>>(detFeatures, wsh + OFF_FC1P, fc1b, f1A);
  kP<<<4096, 256, 0, stream>>>(detScores, dtBoxes, cI, nI, pwb1, pwb2,
      wsh + OFF_W0P, wsh + OFF_W1P, wsh + OFF_W2P, pfp);

  for (int i = 0; i < 8; ++i){
    int last = (i == 7);
    _Float16* fin1  = (i & 1) ? f1B : f1A;
    _Float16* fout1 = (i & 1) ? f1A : f1B;
    kBlk<<<512, 256, 0, stream>>>(pfp, fin1, fout1, nI,
        wsh + OFF_PW1P + i*6144, wsh + OFF_PW2P + i*4096,
        wsh + OFF_POSTP + i*8192, wsh + OFF_POSTP + i*8192 + 4096, wsh + OFF_OUTP + i*8192,
        wsh + OFF_FC1P + ((i+1) & 7)*4096,
        pw1b + i*64, pw2b + i*64, postb + i*128, postb + i*128 + 64, outb + i*128,
        fc1b + ((i+1) & 7)*32,
        (i == 0) ? detFeatures : fbuf, last ? (float*)d_out : fbuf, last ? 0 : 1);
  }
}